// Round 7
// baseline (260.330 us; speedup 1.0000x reference)
//
#include <hip/hip_runtime.h>
#include <cstddef>

typedef unsigned short u16;
typedef unsigned int u32;
typedef __attribute__((ext_vector_type(8))) __bf16 bf16x8;
typedef __attribute__((ext_vector_type(4))) float f32x4;

constexpr int kB = 8, kC = 256, kCI = 128, kN = 4096, kM = 1024;
constexpr float kEPS = 1e-5f;

__device__ __forceinline__ u16 f2bf(float f) {
    u32 u = __float_as_uint(f);
    u32 r = (u + 0x7fffu + ((u >> 16) & 1u)) >> 16;
    return (u16)r;
}

// ---------------------------------------------------------------------------
// prep: weights -> bf16; fold BN scale into Ww; bb = (bw-mean)*sc+beta
// ---------------------------------------------------------------------------
__global__ __launch_bounds__(256) void prep_kernel(const float* __restrict__ Wth,
                                                   const float* __restrict__ Wph,
                                                   const float* __restrict__ Wg,
                                                   const float* __restrict__ Ww,
                                                   const float* __restrict__ bw,
                                                   const float* __restrict__ gamma,
                                                   const float* __restrict__ beta,
                                                   const float* __restrict__ mean,
                                                   const float* __restrict__ var,
                                                   u16* __restrict__ Wthb,
                                                   u16* __restrict__ Wphb,
                                                   u16* __restrict__ Wgb,
                                                   u16* __restrict__ Wwsb,
                                                   float* __restrict__ bb) {
    int idx = blockIdx.x * 256 + threadIdx.x;
    if (idx < 32768) {
        Wthb[idx] = f2bf(Wth[idx]);
    } else if (idx < 65536) {
        int j = idx - 32768; Wphb[j] = f2bf(Wph[j]);
    } else if (idx < 98304) {
        int j = idx - 65536; Wgb[j] = f2bf(Wg[j]);
    } else {
        int j = idx - 98304;
        int co = j >> 7;
        float sc = gamma[co] * rsqrtf(var[co] + kEPS);
        Wwsb[j] = f2bf(Ww[j] * sc);
        if ((j & 127) == 0) bb[co] = (bw[co] - mean[co]) * sc + beta[co];
    }
}

// ---------------------------------------------------------------------------
// MFMA producer conv1x1 body (optionally fused 2x2 avg-pool on input).
// x fp32: POOL=0: [b][256 c][Mn] ; POOL=1: [b][256 c][64][64] (Mn=1024 pooled)
// cmajor=0: out bf16 [b][n][ci]; cmajor=1: out bf16 [b][ci][n]
// block 256 thr / 4 waves; tile 64 px x 128 ci; K-chunks of 64.
// ---------------------------------------------------------------------------
template <int POOL>
__device__ __forceinline__ void conv_body(const float* __restrict__ x,
                                          const u16* __restrict__ Wb,
                                          const float* __restrict__ bias,
                                          u16* __restrict__ out, int Mn,
                                          int cmajor, int b, int n0,
                                          u16* w_lds, u16* x_lds) {
    int t = threadIdx.x;
    int w = t >> 6, lane = t & 63, l15 = lane & 15, quad = lane >> 4;
    int xn = t & 63, cbb = (t >> 6) * 2;

    f32x4 acc[8];
#pragma unroll
    for (int i = 0; i < 8; i++) acc[i] = (f32x4){0.f, 0.f, 0.f, 0.f};

    for (int c0 = 0; c0 < kC; c0 += 64) {
        __syncthreads();
#pragma unroll
        for (int i = 0; i < 4; i++) {
            int u = t + 256 * i;
            int ci = u >> 3, blk = u & 7;
            *(uint4*)&w_lds[ci * 72 + blk * 8] =
                *(const uint4*)&Wb[ci * kC + c0 + blk * 8];
        }
#pragma unroll
        for (int cc = 0; cc < 2; cc++) {
            int cb = cbb + cc;
            float f[8];
            if (POOL) {
                int p = n0 + xn, ph_ = p >> 5, pw_ = p & 31;
#pragma unroll
                for (int j = 0; j < 8; j++) {
                    const float* src = x + ((size_t)(b * kC + c0 + cb * 8 + j) * 64
                                            + 2 * ph_) * 64 + 2 * pw_;
                    float2 a = *(const float2*)src;
                    float2 b2 = *(const float2*)(src + 64);
                    f[j] = 0.25f * (a.x + a.y + b2.x + b2.y);
                }
            } else {
#pragma unroll
                for (int j = 0; j < 8; j++)
                    f[j] = x[(size_t)(b * kC + c0 + cb * 8 + j) * Mn + n0 + xn];
            }
            uint4 pk;
            pk.x = (u32)f2bf(f[0]) | ((u32)f2bf(f[1]) << 16);
            pk.y = (u32)f2bf(f[2]) | ((u32)f2bf(f[3]) << 16);
            pk.z = (u32)f2bf(f[4]) | ((u32)f2bf(f[5]) << 16);
            pk.w = (u32)f2bf(f[6]) | ((u32)f2bf(f[7]) << 16);
            *(uint4*)&x_lds[xn * 64 + ((cb ^ (xn & 7)) * 8)] = pk;
        }
        __syncthreads();

#pragma unroll
        for (int ks = 0; ks < 2; ks++) {
            int px = w * 16 + l15;
            bf16x8 xf = *(const bf16x8*)&x_lds[px * 64 + (((ks * 4 + quad) ^ (px & 7)) * 8)];
#pragma unroll
            for (int ct = 0; ct < 8; ct++) {
                bf16x8 wf = *(const bf16x8*)&w_lds[(ct * 16 + l15) * 72 + ks * 32 + quad * 8];
                if (cmajor)
                    acc[ct] = __builtin_amdgcn_mfma_f32_16x16x32_bf16(xf, wf, acc[ct], 0, 0, 0);
                else
                    acc[ct] = __builtin_amdgcn_mfma_f32_16x16x32_bf16(wf, xf, acc[ct], 0, 0, 0);
            }
        }
    }

    if (cmajor == 0) {
        int px = n0 + w * 16 + l15;
#pragma unroll
        for (int ct = 0; ct < 8; ct++) {
            int ci0 = ct * 16 + quad * 4;
            uint2 pk;
            pk.x = (u32)f2bf(acc[ct][0] + bias[ci0 + 0]) |
                   ((u32)f2bf(acc[ct][1] + bias[ci0 + 1]) << 16);
            pk.y = (u32)f2bf(acc[ct][2] + bias[ci0 + 2]) |
                   ((u32)f2bf(acc[ct][3] + bias[ci0 + 3]) << 16);
            *(uint2*)&out[(size_t)(b * Mn + px) * kCI + ci0] = pk;
        }
    } else {
        int px = n0 + w * 16 + quad * 4;
#pragma unroll
        for (int ct = 0; ct < 8; ct++) {
            int ci = ct * 16 + l15;
            float bs = bias[ci];
            uint2 pk;
            pk.x = (u32)f2bf(acc[ct][0] + bs) | ((u32)f2bf(acc[ct][1] + bs) << 16);
            pk.y = (u32)f2bf(acc[ct][2] + bs) | ((u32)f2bf(acc[ct][3] + bs) << 16);
            *(uint2*)&out[(size_t)(b * kCI + ci) * Mn + px] = pk;
        }
    }
}

// merged convs: bx<64: theta (no pool, n-major); bx<80: phi (pool, n-major);
// else: g (pool, ci-major). grid (96, 8) = 768 blocks -> 3 blocks/CU.
__global__ __launch_bounds__(256) void convs_kernel(const float* __restrict__ kin,
                                                    const float* __restrict__ qin,
                                                    const float* __restrict__ vin,
                                                    const u16* __restrict__ Wthb,
                                                    const u16* __restrict__ Wphb,
                                                    const u16* __restrict__ Wgb,
                                                    const float* __restrict__ bth,
                                                    const float* __restrict__ bph,
                                                    const float* __restrict__ bg,
                                                    u16* __restrict__ theta,
                                                    u16* __restrict__ phi,
                                                    u16* __restrict__ g) {
    __shared__ __align__(16) u16 w_lds[128 * 72];
    __shared__ __align__(16) u16 x_lds[64 * 64];
    int bx = blockIdx.x, b = blockIdx.y;
    if (bx < 64)
        conv_body<0>(kin, Wthb, bth, theta, kN, 0, b, bx * 64, w_lds, x_lds);
    else if (bx < 80)
        conv_body<1>(qin, Wphb, bph, phi, kM, 0, b, (bx - 64) * 64, w_lds, x_lds);
    else
        conv_body<1>(vin, Wgb, bg, g, kM, 1, b, (bx - 80) * 64, w_lds, x_lds);
}

// ---------------------------------------------------------------------------
// Transposed flash attention, bf16 MFMA, software-pipelined staging.
// theta [B][N][CI], phi [B][M][CI], g [B][CI][M] (bf16); y bf16 [B][N][CI].
// S' = phi . theta^T (C-col = n), O' = G^T . P' (C-col = n).
// 256 thr / 4 waves; wave owns 16 n; m-chunks of 64; double-buffered LDS,
// ONE barrier per chunk, next chunk's global loads in flight during compute.
// P' reaches the O' B-operand via 16 shuffles (no LDS round-trip).
// ---------------------------------------------------------------------------
__global__ __launch_bounds__(256) void attn_kernel(const u16* __restrict__ theta,
                                                   const u16* __restrict__ phi,
                                                   const u16* __restrict__ g,
                                                   u16* __restrict__ y) {
    __shared__ __align__(16) u16 ph_lds[2 * 8192];   // [buf][ks:4][m:64][kblk^sw][8]
    __shared__ __align__(16) u16 g_lds[2 * 8192];    // [buf][ks2:2][ci:128][kblk^sw][8]

    int t = threadIdx.x, b = blockIdx.y, n0 = blockIdx.x * 64;
    int w = t >> 6, lane = t & 63, l15 = lane & 15, quad = lane >> 4;
    int sw = (l15 >> 1) & 3;

    // theta B-frags in registers for the whole kernel (16 n per wave)
    bf16x8 thf[4];
    const u16* thB = theta + ((size_t)(b * kN) + n0 + w * 16 + l15) * kCI;
#pragma unroll
    for (int ks = 0; ks < 4; ks++)
        thf[ks] = *(const bf16x8*)&thB[ks * 32 + quad * 8];

    f32x4 oacc[8];
#pragma unroll
    for (int ct = 0; ct < 8; ct++) oacc[ct] = (f32x4){0.f, 0.f, 0.f, 0.f};
    float m_ = -1e30f, l_ = 0.f;

    const u16* phB = phi + (size_t)b * kM * kCI;
    const u16* gB  = g   + (size_t)b * kCI * kM;

    // prefetch registers for next chunk
    uint4 phr[4], gr[4];
#pragma unroll
    for (int it = 0; it < 4; it++) {
        int u = t + 256 * it;
        phr[it] = *(const uint4*)&phB[(size_t)(u >> 4) * kCI + (u & 15) * 8];
        gr[it]  = *(const uint4*)&gB[(size_t)(u >> 3) * kM + (u & 7) * 8];
    }

    for (int cidx = 0; cidx < 16; cidx++) {
        u16* phb = ph_lds + (cidx & 1) * 8192;
        u16* gbL = g_lds + (cidx & 1) * 8192;
        // write prefetched chunk into this buffer (swizzled)
#pragma unroll
        for (int it = 0; it < 4; it++) {
            int u = t + 256 * it;
            int row = u >> 4, cb = u & 15;
            *(uint4*)&phb[(cb >> 2) * 2048 + row * 32 + (((cb & 3) ^ ((row >> 1) & 3)) * 8)] = phr[it];
            int ci = u >> 3, mb = u & 7;
            *(uint4*)&gbL[(mb >> 2) * 4096 + ci * 32 + (((mb & 3) ^ ((ci >> 1) & 3)) * 8)] = gr[it];
        }
        // issue next chunk's global loads (consumed next iteration)
        if (cidx < 15) {
            int c0n = (cidx + 1) * 64;
#pragma unroll
            for (int it = 0; it < 4; it++) {
                int u = t + 256 * it;
                phr[it] = *(const uint4*)&phB[(size_t)(c0n + (u >> 4)) * kCI + (u & 15) * 8];
                gr[it]  = *(const uint4*)&gB[(size_t)(u >> 3) * kM + c0n + (u & 7) * 8];
            }
        }
        __syncthreads();

        // S' = phi(64m x 128k) . theta^T : 4 mt-tiles, C-col = n
        f32x4 sacc[4];
#pragma unroll
        for (int mt = 0; mt < 4; mt++) sacc[mt] = (f32x4){0.f, 0.f, 0.f, 0.f};
#pragma unroll
        for (int ks = 0; ks < 4; ks++)
#pragma unroll
            for (int mt = 0; mt < 4; mt++) {
                bf16x8 a = *(const bf16x8*)&phb[ks * 2048 + (mt * 16 + l15) * 32 +
                                                ((quad ^ sw) * 8)];
                sacc[mt] = __builtin_amdgcn_mfma_f32_16x16x32_bf16(a, thf[ks], sacc[mt], 0, 0, 0);
            }

        // online softmax over m (per-lane n = l15; reduce across quads)
        float mc = -1e30f;
#pragma unroll
        for (int mt = 0; mt < 4; mt++)
#pragma unroll
            for (int r = 0; r < 4; r++) mc = fmaxf(mc, sacc[mt][r]);
        mc = fmaxf(mc, __shfl_xor(mc, 16, 64));
        mc = fmaxf(mc, __shfl_xor(mc, 32, 64));
        float mn = fmaxf(m_, mc);
        int resc = __any(mn != m_);
        float alpha = __expf(m_ - mn);
        m_ = mn;
        float rs = 0.f;
#pragma unroll
        for (int mt = 0; mt < 4; mt++)
#pragma unroll
            for (int r = 0; r < 4; r++) {
                float p = __expf(sacc[mt][r] - mn);
                sacc[mt][r] = p;
                rs += p;
            }
        rs += __shfl_xor(rs, 16, 64);
        rs += __shfl_xor(rs, 32, 64);
        l_ = l_ * alpha + rs;
        if (resc) {
#pragma unroll
            for (int ct = 0; ct < 8; ct++)
#pragma unroll
                for (int r = 0; r < 4; r++) oacc[ct][r] *= alpha;
        }

        // pack P' pairs: d[mt][h] = P[m=mt*16+quad*4+2h .. +1][n=l15]
        u32 d[4][2];
#pragma unroll
        for (int mt = 0; mt < 4; mt++)
#pragma unroll
            for (int h = 0; h < 2; h++)
                d[mt][h] = (u32)f2bf(sacc[mt][2 * h]) |
                           ((u32)f2bf(sacc[mt][2 * h + 1]) << 16);

        // O' += G^T(128ci x 64m) . P'(64m x n): B-frags via shuffles
#pragma unroll
        for (int ks2 = 0; ks2 < 2; ks2++) {
            union { u32 u[4]; bf16x8 v; } bu;
#pragma unroll
            for (int jj = 0; jj < 4; jj++) {
                int srcl = 16 * ((quad & 1) * 2 + (jj >> 1)) + l15;
                u32 va = (u32)__shfl((int)d[ks2 * 2 + 0][jj & 1], srcl, 64);
                u32 vb = (u32)__shfl((int)d[ks2 * 2 + 1][jj & 1], srcl, 64);
                bu.u[jj] = (quad >> 1) ? vb : va;
            }
#pragma unroll
            for (int ct = 0; ct < 8; ct++) {
                bf16x8 a = *(const bf16x8*)&gbL[ks2 * 4096 + (ct * 16 + l15) * 32 +
                                                ((quad ^ sw) * 8)];
                oacc[ct] = __builtin_amdgcn_mfma_f32_16x16x32_bf16(a, bu.v, oacc[ct], 0, 0, 0);
            }
        }
    }

    // epilogue: y[n][ci] = O'/l ; n = col = l15
    float inv = 1.0f / l_;
    int n = n0 + w * 16 + l15;
    u16* yr = y + ((size_t)(b * kN) + n) * kCI + quad * 4;
#pragma unroll
    for (int ct = 0; ct < 8; ct++) {
        uint2 pk;
        pk.x = (u32)f2bf(oacc[ct][0] * inv) | ((u32)f2bf(oacc[ct][1] * inv) << 16);
        pk.y = (u32)f2bf(oacc[ct][2] * inv) | ((u32)f2bf(oacc[ct][3] * inv) << 16);
        *(uint2*)&yr[ct * 16] = pk;
    }
}

// ---------------------------------------------------------------------------
// MFMA final conv: out[b][co][n] = Wws(bf16 [256][128]) . y(bf16 [b][n][128])
//                  + bb[co] + v[b][co][n]   (fp32 out)
// 32-px tiles, grid (128,8)=1024 blocks -> 4 blocks/CU. 4 waves: wave w covers
// px-half (w&1) and co-half (w>>1).
// ---------------------------------------------------------------------------
__global__ __launch_bounds__(256) void final_kernel(const u16* __restrict__ y,
                                                    const u16* __restrict__ Wws,
                                                    const float* __restrict__ bb,
                                                    const float* __restrict__ v,
                                                    float* __restrict__ out) {
    __shared__ __align__(16) u16 y_lds[32 * 136];
    int t = threadIdx.x, b = blockIdx.y, n0 = blockIdx.x * 32;
    int w = t >> 6, lane = t & 63, l15 = lane & 15, quad = lane >> 4;

#pragma unroll
    for (int i = 0; i < 2; i++) {
        int u = t + 256 * i;
        int row = u >> 4, blk = u & 15;
        *(uint4*)&y_lds[row * 136 + blk * 8] =
            *(const uint4*)&y[(size_t)(b * kN + n0 + row) * kCI + blk * 8];
    }
    __syncthreads();

    int p = w & 1, coh = (w >> 1) * 8;
    bf16x8 af[4];
#pragma unroll
    for (int ks = 0; ks < 4; ks++)
        af[ks] = *(const bf16x8*)&y_lds[(p * 16 + l15) * 136 + ks * 32 + quad * 8];

#pragma unroll
    for (int ct2 = 0; ct2 < 8; ct2++) {
        int ct = coh + ct2;
        f32x4 a = (f32x4){0.f, 0.f, 0.f, 0.f};
#pragma unroll
        for (int ks = 0; ks < 4; ks++) {
            bf16x8 bf = *(const bf16x8*)&Wws[(ct * 16 + l15) * kCI + ks * 32 + quad * 8];
            a = __builtin_amdgcn_mfma_f32_16x16x32_bf16(af[ks], bf, a, 0, 0, 0);
        }
        int co = ct * 16 + l15;
        float bbv = bb[co];
        size_t base = (size_t)(b * kC + co) * kN + n0 + p * 16 + quad * 4;
        float4 vv = *(const float4*)&v[base];
        float4 ov;
        ov.x = a[0] + bbv + vv.x;
        ov.y = a[1] + bbv + vv.y;
        ov.z = a[2] + bbv + vv.z;
        ov.w = a[3] + bbv + vv.w;
        *(float4*)&out[base] = ov;
    }
}

// ---------------------------------------------------------------------------
extern "C" void kernel_launch(void* const* d_in, const int* in_sizes, int n_in,
                              void* d_out, int out_size, void* d_ws, size_t ws_size,
                              hipStream_t stream) {
    (void)in_sizes; (void)n_in; (void)out_size; (void)ws_size;
    const float* q     = (const float*)d_in[0];
    const float* k     = (const float*)d_in[1];
    const float* v     = (const float*)d_in[2];
    const float* Wg    = (const float*)d_in[3];
    const float* bg    = (const float*)d_in[4];
    const float* Wth   = (const float*)d_in[5];
    const float* bth   = (const float*)d_in[6];
    const float* Wph   = (const float*)d_in[7];
    const float* bph   = (const float*)d_in[8];
    const float* Ww    = (const float*)d_in[9];
    const float* bw    = (const float*)d_in[10];
    const float* gamma = (const float*)d_in[11];
    const float* beta  = (const float*)d_in[12];
    const float* mean  = (const float*)d_in[13];
    const float* var   = (const float*)d_in[14];
    float* out = (float*)d_out;

    u16* wsu = (u16*)d_ws;
    u16*   theta = wsu;                       // 4M u16
    u16*   phi   = theta + 4194304;           // 1M u16
    u16*   gbuf  = phi + 1048576;             // 1M u16
    u16*   ybuf  = gbuf + 1048576;            // 4M u16
    u16*   Wthb  = ybuf + 4194304;
    u16*   Wphb  = Wthb + 32768;
    u16*   Wgb   = Wphb + 32768;
    u16*   Wwsb  = Wgb + 32768;
    float* bbuf  = (float*)(Wwsb + 32768);

    prep_kernel<<<dim3(512), 256, 0, stream>>>(Wth, Wph, Wg, Ww, bw, gamma, beta,
                                               mean, var, Wthb, Wphb, Wgb, Wwsb, bbuf);
    convs_kernel<<<dim3(96, 8), 256, 0, stream>>>(k, q, v, Wthb, Wphb, Wgb,
                                                  bth, bph, bg, theta, phi, gbuf);
    attn_kernel<<<dim3(64, 8), 256, 0, stream>>>(theta, phi, gbuf, ybuf);
    final_kernel<<<dim3(128, 8), 256, 0, stream>>>(ybuf, Wwsb, bbuf, v, out);
}

// Round 8
// 260.268 us; speedup vs baseline: 1.0002x; 1.0002x over previous
//
#include <hip/hip_runtime.h>
#include <cstddef>

typedef unsigned short u16;
typedef unsigned int u32;
typedef __attribute__((ext_vector_type(8))) __bf16 bf16x8;
typedef __attribute__((ext_vector_type(4))) float f32x4;

constexpr int kB = 8, kC = 256, kCI = 128, kN = 4096, kM = 1024;
constexpr float kEPS = 1e-5f;

__device__ __forceinline__ u16 f2bf(float f) {
    u32 u = __float_as_uint(f);
    u32 r = (u + 0x7fffu + ((u >> 16) & 1u)) >> 16;
    return (u16)r;
}

// ---------------------------------------------------------------------------
// prep: weights -> bf16; fold BN scale into Ww; bb = (bw-mean)*sc+beta
// ---------------------------------------------------------------------------
__global__ __launch_bounds__(256) void prep_kernel(const float* __restrict__ Wth,
                                                   const float* __restrict__ Wph,
                                                   const float* __restrict__ Wg,
                                                   const float* __restrict__ Ww,
                                                   const float* __restrict__ bw,
                                                   const float* __restrict__ gamma,
                                                   const float* __restrict__ beta,
                                                   const float* __restrict__ mean,
                                                   const float* __restrict__ var,
                                                   u16* __restrict__ Wthb,
                                                   u16* __restrict__ Wphb,
                                                   u16* __restrict__ Wgb,
                                                   u16* __restrict__ Wwsb,
                                                   float* __restrict__ bb) {
    int idx = blockIdx.x * 256 + threadIdx.x;
    if (idx < 32768) {
        Wthb[idx] = f2bf(Wth[idx]);
    } else if (idx < 65536) {
        int j = idx - 32768; Wphb[j] = f2bf(Wph[j]);
    } else if (idx < 98304) {
        int j = idx - 65536; Wgb[j] = f2bf(Wg[j]);
    } else {
        int j = idx - 98304;
        int co = j >> 7;
        float sc = gamma[co] * rsqrtf(var[co] + kEPS);
        Wwsb[j] = f2bf(Ww[j] * sc);
        if ((j & 127) == 0) bb[co] = (bw[co] - mean[co]) * sc + beta[co];
    }
}

// ---------------------------------------------------------------------------
// MFMA producer conv1x1 body (optionally fused 2x2 avg-pool on input).
// x fp32: POOL=0: [b][256 c][Mn] ; POOL=1: [b][256 c][64][64] (Mn=1024 pooled)
// cmajor=0: out bf16 [b][n][ci]; cmajor=1: out bf16 [b][ci][n]
// block 256 thr / 4 waves; tile 64 px x 128 ci; K-chunks of 64.
// ---------------------------------------------------------------------------
template <int POOL>
__device__ __forceinline__ void conv_body(const float* __restrict__ x,
                                          const u16* __restrict__ Wb,
                                          const float* __restrict__ bias,
                                          u16* __restrict__ out, int Mn,
                                          int cmajor, int b, int n0,
                                          u16* w_lds, u16* x_lds) {
    int t = threadIdx.x;
    int w = t >> 6, lane = t & 63, l15 = lane & 15, quad = lane >> 4;
    int xn = t & 63, cbb = (t >> 6) * 2;

    f32x4 acc[8];
#pragma unroll
    for (int i = 0; i < 8; i++) acc[i] = (f32x4){0.f, 0.f, 0.f, 0.f};

    for (int c0 = 0; c0 < kC; c0 += 64) {
        __syncthreads();
#pragma unroll
        for (int i = 0; i < 4; i++) {
            int u = t + 256 * i;
            int ci = u >> 3, blk = u & 7;
            *(uint4*)&w_lds[ci * 72 + blk * 8] =
                *(const uint4*)&Wb[ci * kC + c0 + blk * 8];
        }
#pragma unroll
        for (int cc = 0; cc < 2; cc++) {
            int cb = cbb + cc;
            float f[8];
            if (POOL) {
                int p = n0 + xn, ph_ = p >> 5, pw_ = p & 31;
#pragma unroll
                for (int j = 0; j < 8; j++) {
                    const float* src = x + ((size_t)(b * kC + c0 + cb * 8 + j) * 64
                                            + 2 * ph_) * 64 + 2 * pw_;
                    float2 a = *(const float2*)src;
                    float2 b2 = *(const float2*)(src + 64);
                    f[j] = 0.25f * (a.x + a.y + b2.x + b2.y);
                }
            } else {
#pragma unroll
                for (int j = 0; j < 8; j++)
                    f[j] = x[(size_t)(b * kC + c0 + cb * 8 + j) * Mn + n0 + xn];
            }
            uint4 pk;
            pk.x = (u32)f2bf(f[0]) | ((u32)f2bf(f[1]) << 16);
            pk.y = (u32)f2bf(f[2]) | ((u32)f2bf(f[3]) << 16);
            pk.z = (u32)f2bf(f[4]) | ((u32)f2bf(f[5]) << 16);
            pk.w = (u32)f2bf(f[6]) | ((u32)f2bf(f[7]) << 16);
            *(uint4*)&x_lds[xn * 64 + ((cb ^ (xn & 7)) * 8)] = pk;
        }
        __syncthreads();

#pragma unroll
        for (int ks = 0; ks < 2; ks++) {
            int px = w * 16 + l15;
            bf16x8 xf = *(const bf16x8*)&x_lds[px * 64 + (((ks * 4 + quad) ^ (px & 7)) * 8)];
#pragma unroll
            for (int ct = 0; ct < 8; ct++) {
                bf16x8 wf = *(const bf16x8*)&w_lds[(ct * 16 + l15) * 72 + ks * 32 + quad * 8];
                if (cmajor)
                    acc[ct] = __builtin_amdgcn_mfma_f32_16x16x32_bf16(xf, wf, acc[ct], 0, 0, 0);
                else
                    acc[ct] = __builtin_amdgcn_mfma_f32_16x16x32_bf16(wf, xf, acc[ct], 0, 0, 0);
            }
        }
    }

    if (cmajor == 0) {
        int px = n0 + w * 16 + l15;
#pragma unroll
        for (int ct = 0; ct < 8; ct++) {
            int ci0 = ct * 16 + quad * 4;
            uint2 pk;
            pk.x = (u32)f2bf(acc[ct][0] + bias[ci0 + 0]) |
                   ((u32)f2bf(acc[ct][1] + bias[ci0 + 1]) << 16);
            pk.y = (u32)f2bf(acc[ct][2] + bias[ci0 + 2]) |
                   ((u32)f2bf(acc[ct][3] + bias[ci0 + 3]) << 16);
            *(uint2*)&out[(size_t)(b * Mn + px) * kCI + ci0] = pk;
        }
    } else {
        int px = n0 + w * 16 + quad * 4;
#pragma unroll
        for (int ct = 0; ct < 8; ct++) {
            int ci = ct * 16 + l15;
            float bs = bias[ci];
            uint2 pk;
            pk.x = (u32)f2bf(acc[ct][0] + bs) | ((u32)f2bf(acc[ct][1] + bs) << 16);
            pk.y = (u32)f2bf(acc[ct][2] + bs) | ((u32)f2bf(acc[ct][3] + bs) << 16);
            *(uint2*)&out[(size_t)(b * kCI + ci) * Mn + px] = pk;
        }
    }
}

// merged convs: bx<64: theta (no pool, n-major); bx<80: phi (pool, n-major);
// else: g (pool, ci-major). grid (96, 8) = 768 blocks -> 3 blocks/CU.
__global__ __launch_bounds__(256) void convs_kernel(const float* __restrict__ kin,
                                                    const float* __restrict__ qin,
                                                    const float* __restrict__ vin,
                                                    const u16* __restrict__ Wthb,
                                                    const u16* __restrict__ Wphb,
                                                    const u16* __restrict__ Wgb,
                                                    const float* __restrict__ bth,
                                                    const float* __restrict__ bph,
                                                    const float* __restrict__ bg,
                                                    u16* __restrict__ theta,
                                                    u16* __restrict__ phi,
                                                    u16* __restrict__ g) {
    __shared__ __align__(16) u16 w_lds[128 * 72];
    __shared__ __align__(16) u16 x_lds[64 * 64];
    int bx = blockIdx.x, b = blockIdx.y;
    if (bx < 64)
        conv_body<0>(kin, Wthb, bth, theta, kN, 0, b, bx * 64, w_lds, x_lds);
    else if (bx < 80)
        conv_body<1>(qin, Wphb, bph, phi, kM, 0, b, (bx - 64) * 64, w_lds, x_lds);
    else
        conv_body<1>(vin, Wgb, bg, g, kM, 1, b, (bx - 80) * 64, w_lds, x_lds);
}

// ---------------------------------------------------------------------------
// Barrier-free streaming flash attention, bf16 MFMA, ZERO LDS.
// theta [B][N][CI], phi [B][M][CI], g [B][CI][M] (bf16); y bf16 [B][N][CI].
// One wave per block (64 thr); wave owns 32 n; m-chunks of 64.
// S' = phi . theta^T (C-col = n): phi A-frags streamed from L2 (contiguous
// 16B along ci), theta B-frags register-resident.  P' C-layout -> B-operand
// via 8 ds_bpermute per (nt,ks2) (R7 formula, verified).  O' = G^T . P':
// g A-frags streamed from L2 (contiguous 16B along m).  No __syncthreads.
// ---------------------------------------------------------------------------
__global__ __launch_bounds__(64, 1) void attn_kernel(const u16* __restrict__ theta,
                                                     const u16* __restrict__ phi,
                                                     const u16* __restrict__ g,
                                                     u16* __restrict__ y) {
    int b = blockIdx.y, n0 = blockIdx.x * 32;
    int lane = threadIdx.x & 63, l15 = lane & 15, quad = lane >> 4;

    const u16* phB = phi + (size_t)b * kM * kCI;
    const u16* gB  = g   + (size_t)b * kCI * kM;

    // theta B-frags: register-resident for the whole kernel (32 n per wave)
    bf16x8 thf[2][4];
    const u16* thB = theta + ((size_t)(b * kN) + n0) * kCI;
#pragma unroll
    for (int nt = 0; nt < 2; nt++)
#pragma unroll
        for (int ks = 0; ks < 4; ks++)
            thf[nt][ks] = *(const bf16x8*)&thB[(size_t)(nt * 16 + l15) * kCI + ks * 32 + quad * 8];

    f32x4 oacc[8][2];
#pragma unroll
    for (int ct = 0; ct < 8; ct++) {
        oacc[ct][0] = (f32x4){0.f, 0.f, 0.f, 0.f};
        oacc[ct][1] = (f32x4){0.f, 0.f, 0.f, 0.f};
    }
    float m_[2] = {-1e30f, -1e30f}, l_[2] = {0.f, 0.f};

    for (int c0 = 0; c0 < kM; c0 += 64) {
        // ---- S' = phi(64m x 128k) . theta^T ; phi A-frags from global ----
        bf16x8 pf[4][4];
#pragma unroll
        for (int mt = 0; mt < 4; mt++)
#pragma unroll
            for (int ks = 0; ks < 4; ks++)
                pf[mt][ks] = *(const bf16x8*)&phB[(size_t)(c0 + mt * 16 + l15) * kCI +
                                                  ks * 32 + quad * 8];
        f32x4 sacc[4][2];
#pragma unroll
        for (int mt = 0; mt < 4; mt++) {
            sacc[mt][0] = (f32x4){0.f, 0.f, 0.f, 0.f};
            sacc[mt][1] = (f32x4){0.f, 0.f, 0.f, 0.f};
        }
#pragma unroll
        for (int ks = 0; ks < 4; ks++)
#pragma unroll
            for (int mt = 0; mt < 4; mt++) {
                sacc[mt][0] = __builtin_amdgcn_mfma_f32_16x16x32_bf16(pf[mt][ks], thf[0][ks],
                                                                      sacc[mt][0], 0, 0, 0);
                sacc[mt][1] = __builtin_amdgcn_mfma_f32_16x16x32_bf16(pf[mt][ks], thf[1][ks],
                                                                      sacc[mt][1], 0, 0, 0);
            }

        // ---- online softmax per nt (C-col = n = l15; rows m across quad,reg)
        u32 d[2][4][2];   // [nt][mt][h]: P[m=mt*16+quad*4+2h..+1][n=l15] packed
#pragma unroll
        for (int nt = 0; nt < 2; nt++) {
            float mc = -1e30f;
#pragma unroll
            for (int mt = 0; mt < 4; mt++)
#pragma unroll
                for (int r = 0; r < 4; r++) mc = fmaxf(mc, sacc[mt][nt][r]);
            mc = fmaxf(mc, __shfl_xor(mc, 16, 64));
            mc = fmaxf(mc, __shfl_xor(mc, 32, 64));
            float mn = fmaxf(m_[nt], mc);
            int resc = __any(mn != m_[nt]);
            float alpha = __expf(m_[nt] - mn);
            m_[nt] = mn;
            float rs = 0.f;
#pragma unroll
            for (int mt = 0; mt < 4; mt++)
#pragma unroll
                for (int r = 0; r < 4; r++) {
                    float p = __expf(sacc[mt][nt][r] - mn);
                    sacc[mt][nt][r] = p;
                    rs += p;
                }
            rs += __shfl_xor(rs, 16, 64);
            rs += __shfl_xor(rs, 32, 64);
            l_[nt] = l_[nt] * alpha + rs;
            if (resc) {
#pragma unroll
                for (int ct = 0; ct < 8; ct++)
#pragma unroll
                    for (int r = 0; r < 4; r++) oacc[ct][nt][r] *= alpha;
            }
#pragma unroll
            for (int mt = 0; mt < 4; mt++)
#pragma unroll
                for (int h = 0; h < 2; h++)
                    d[nt][mt][h] = (u32)f2bf(sacc[mt][nt][2 * h]) |
                                   ((u32)f2bf(sacc[mt][nt][2 * h + 1]) << 16);
        }

        // ---- O' += G^T(128ci x 64m) . P'(64m x 32n); g A-frags from global
#pragma unroll
        for (int ks2 = 0; ks2 < 2; ks2++) {
            union { u32 u[4]; bf16x8 v; } bu[2];
#pragma unroll
            for (int nt = 0; nt < 2; nt++)
#pragma unroll
                for (int jj = 0; jj < 4; jj++) {
                    int srcl = 16 * ((quad & 1) * 2 + (jj >> 1)) + l15;
                    u32 va = (u32)__shfl((int)d[nt][ks2 * 2 + 0][jj & 1], srcl, 64);
                    u32 vb = (u32)__shfl((int)d[nt][ks2 * 2 + 1][jj & 1], srcl, 64);
                    bu[nt].u[jj] = (quad >> 1) ? vb : va;
                }
#pragma unroll
            for (int ct = 0; ct < 8; ct++) {
                bf16x8 a = *(const bf16x8*)&gB[(size_t)(ct * 16 + l15) * kM + c0 +
                                               ks2 * 32 + quad * 8];
                oacc[ct][0] = __builtin_amdgcn_mfma_f32_16x16x32_bf16(a, bu[0].v, oacc[ct][0], 0, 0, 0);
                oacc[ct][1] = __builtin_amdgcn_mfma_f32_16x16x32_bf16(a, bu[1].v, oacc[ct][1], 0, 0, 0);
            }
        }
    }

    // ---- epilogue: y[n][ci] = O'/l ; n = col = l15
#pragma unroll
    for (int nt = 0; nt < 2; nt++) {
        float inv = 1.0f / l_[nt];
        int n = n0 + nt * 16 + l15;
        u16* yr = y + ((size_t)(b * kN) + n) * kCI + quad * 4;
#pragma unroll
        for (int ct = 0; ct < 8; ct++) {
            uint2 pk;
            pk.x = (u32)f2bf(oacc[ct][nt][0] * inv) | ((u32)f2bf(oacc[ct][nt][1] * inv) << 16);
            pk.y = (u32)f2bf(oacc[ct][nt][2] * inv) | ((u32)f2bf(oacc[ct][nt][3] * inv) << 16);
            *(uint2*)&yr[ct * 16] = pk;
        }
    }
}

// ---------------------------------------------------------------------------
// Barrier-free MFMA final conv: out[b][co][n] = Wws . y + bb[co] + v  (fp32)
// One wave per block; wave owns 16 n x 256 co; y A-frags + W B-frags streamed
// straight from L2 (both contiguous 16B). No LDS, no barrier.
// ---------------------------------------------------------------------------
__global__ __launch_bounds__(64, 1) void final_kernel(const u16* __restrict__ y,
                                                      const u16* __restrict__ Wws,
                                                      const float* __restrict__ bb,
                                                      const float* __restrict__ v,
                                                      float* __restrict__ out) {
    int b = blockIdx.y, n0 = blockIdx.x * 16;
    int lane = threadIdx.x & 63, l15 = lane & 15, quad = lane >> 4;

    bf16x8 af[4];
#pragma unroll
    for (int ks = 0; ks < 4; ks++)
        af[ks] = *(const bf16x8*)&y[(size_t)(b * kN + n0 + l15) * kCI + ks * 32 + quad * 8];

#pragma unroll
    for (int ct = 0; ct < 16; ct++) {
        f32x4 a = (f32x4){0.f, 0.f, 0.f, 0.f};
#pragma unroll
        for (int ks = 0; ks < 4; ks++) {
            bf16x8 bf = *(const bf16x8*)&Wws[(ct * 16 + l15) * kCI + ks * 32 + quad * 8];
            a = __builtin_amdgcn_mfma_f32_16x16x32_bf16(af[ks], bf, a, 0, 0, 0);
        }
        int co = ct * 16 + l15;
        float bbv = bb[co];
        size_t base = (size_t)(b * kC + co) * kN + n0 + quad * 4;
        float4 vv = *(const float4*)&v[base];
        float4 ov;
        ov.x = a[0] + bbv + vv.x;
        ov.y = a[1] + bbv + vv.y;
        ov.z = a[2] + bbv + vv.z;
        ov.w = a[3] + bbv + vv.w;
        *(float4*)&out[base] = ov;
    }
}

// ---------------------------------------------------------------------------
extern "C" void kernel_launch(void* const* d_in, const int* in_sizes, int n_in,
                              void* d_out, int out_size, void* d_ws, size_t ws_size,
                              hipStream_t stream) {
    (void)in_sizes; (void)n_in; (void)out_size; (void)ws_size;
    const float* q     = (const float*)d_in[0];
    const float* k     = (const float*)d_in[1];
    const float* v     = (const float*)d_in[2];
    const float* Wg    = (const float*)d_in[3];
    const float* bg    = (const float*)d_in[4];
    const float* Wth   = (const float*)d_in[5];
    const float* bth   = (const float*)d_in[6];
    const float* Wph   = (const float*)d_in[7];
    const float* bph   = (const float*)d_in[8];
    const float* Ww    = (const float*)d_in[9];
    const float* bw    = (const float*)d_in[10];
    const float* gamma = (const float*)d_in[11];
    const float* beta  = (const float*)d_in[12];
    const float* mean  = (const float*)d_in[13];
    const float* var   = (const float*)d_in[14];
    float* out = (float*)d_out;

    u16* wsu = (u16*)d_ws;
    u16*   theta = wsu;                       // 4M u16
    u16*   phi   = theta + 4194304;           // 1M u16
    u16*   gbuf  = phi + 1048576;             // 1M u16
    u16*   ybuf  = gbuf + 1048576;            // 4M u16
    u16*   Wthb  = ybuf + 4194304;
    u16*   Wphb  = Wthb + 32768;
    u16*   Wgb   = Wphb + 32768;
    u16*   Wwsb  = Wgb + 32768;
    float* bbuf  = (float*)(Wwsb + 32768);

    prep_kernel<<<dim3(512), 256, 0, stream>>>(Wth, Wph, Wg, Ww, bw, gamma, beta,
                                               mean, var, Wthb, Wphb, Wgb, Wwsb, bbuf);
    convs_kernel<<<dim3(96, 8), 256, 0, stream>>>(k, q, v, Wthb, Wphb, Wgb,
                                                  bth, bph, bg, theta, phi, gbuf);
    attn_kernel<<<dim3(128, 8), 64, 0, stream>>>(theta, phi, gbuf, ybuf);
    final_kernel<<<dim3(256, 8), 64, 0, stream>>>(ybuf, Wwsb, bbuf, v, out);
}

// Round 9
// 259.187 us; speedup vs baseline: 1.0044x; 1.0042x over previous
//
#include <hip/hip_runtime.h>
#include <cstddef>

typedef unsigned short u16;
typedef unsigned int u32;
typedef __attribute__((ext_vector_type(8))) __bf16 bf16x8;
typedef __attribute__((ext_vector_type(4))) float f32x4;

constexpr int kB = 8, kC = 256, kCI = 128, kN = 4096, kM = 1024;
constexpr float kEPS = 1e-5f;

__device__ __forceinline__ u16 f2bf(float f) {
    u32 u = __float_as_uint(f);
    u32 r = (u + 0x7fffu + ((u >> 16) & 1u)) >> 16;
    return (u16)r;
}

// ---------------------------------------------------------------------------
// prep: weights -> bf16; fold BN scale into Ww; bb = (bw-mean)*sc+beta
// ---------------------------------------------------------------------------
__global__ __launch_bounds__(256) void prep_kernel(const float* __restrict__ Wth,
                                                   const float* __restrict__ Wph,
                                                   const float* __restrict__ Wg,
                                                   const float* __restrict__ Ww,
                                                   const float* __restrict__ bw,
                                                   const float* __restrict__ gamma,
                                                   const float* __restrict__ beta,
                                                   const float* __restrict__ mean,
                                                   const float* __restrict__ var,
                                                   u16* __restrict__ Wthb,
                                                   u16* __restrict__ Wphb,
                                                   u16* __restrict__ Wgb,
                                                   u16* __restrict__ Wwsb,
                                                   float* __restrict__ bb) {
    int idx = blockIdx.x * 256 + threadIdx.x;
    if (idx < 32768) {
        Wthb[idx] = f2bf(Wth[idx]);
    } else if (idx < 65536) {
        int j = idx - 32768; Wphb[j] = f2bf(Wph[j]);
    } else if (idx < 98304) {
        int j = idx - 65536; Wgb[j] = f2bf(Wg[j]);
    } else {
        int j = idx - 98304;
        int co = j >> 7;
        float sc = gamma[co] * rsqrtf(var[co] + kEPS);
        Wwsb[j] = f2bf(Ww[j] * sc);
        if ((j & 127) == 0) bb[co] = (bw[co] - mean[co]) * sc + beta[co];
    }
}

// ---------------------------------------------------------------------------
// MFMA producer conv1x1 body (optionally fused 2x2 avg-pool on input).
// ---------------------------------------------------------------------------
template <int POOL>
__device__ __forceinline__ void conv_body(const float* __restrict__ x,
                                          const u16* __restrict__ Wb,
                                          const float* __restrict__ bias,
                                          u16* __restrict__ out, int Mn,
                                          int cmajor, int b, int n0,
                                          u16* w_lds, u16* x_lds) {
    int t = threadIdx.x;
    int w = t >> 6, lane = t & 63, l15 = lane & 15, quad = lane >> 4;
    int xn = t & 63, cbb = (t >> 6) * 2;

    f32x4 acc[8];
#pragma unroll
    for (int i = 0; i < 8; i++) acc[i] = (f32x4){0.f, 0.f, 0.f, 0.f};

    for (int c0 = 0; c0 < kC; c0 += 64) {
        __syncthreads();
#pragma unroll
        for (int i = 0; i < 4; i++) {
            int u = t + 256 * i;
            int ci = u >> 3, blk = u & 7;
            *(uint4*)&w_lds[ci * 72 + blk * 8] =
                *(const uint4*)&Wb[ci * kC + c0 + blk * 8];
        }
#pragma unroll
        for (int cc = 0; cc < 2; cc++) {
            int cb = cbb + cc;
            float f[8];
            if (POOL) {
                int p = n0 + xn, ph_ = p >> 5, pw_ = p & 31;
#pragma unroll
                for (int j = 0; j < 8; j++) {
                    const float* src = x + ((size_t)(b * kC + c0 + cb * 8 + j) * 64
                                            + 2 * ph_) * 64 + 2 * pw_;
                    float2 a = *(const float2*)src;
                    float2 b2 = *(const float2*)(src + 64);
                    f[j] = 0.25f * (a.x + a.y + b2.x + b2.y);
                }
            } else {
#pragma unroll
                for (int j = 0; j < 8; j++)
                    f[j] = x[(size_t)(b * kC + c0 + cb * 8 + j) * Mn + n0 + xn];
            }
            uint4 pk;
            pk.x = (u32)f2bf(f[0]) | ((u32)f2bf(f[1]) << 16);
            pk.y = (u32)f2bf(f[2]) | ((u32)f2bf(f[3]) << 16);
            pk.z = (u32)f2bf(f[4]) | ((u32)f2bf(f[5]) << 16);
            pk.w = (u32)f2bf(f[6]) | ((u32)f2bf(f[7]) << 16);
            *(uint4*)&x_lds[xn * 64 + ((cb ^ (xn & 7)) * 8)] = pk;
        }
        __syncthreads();

#pragma unroll
        for (int ks = 0; ks < 2; ks++) {
            int px = w * 16 + l15;
            bf16x8 xf = *(const bf16x8*)&x_lds[px * 64 + (((ks * 4 + quad) ^ (px & 7)) * 8)];
#pragma unroll
            for (int ct = 0; ct < 8; ct++) {
                bf16x8 wf = *(const bf16x8*)&w_lds[(ct * 16 + l15) * 72 + ks * 32 + quad * 8];
                if (cmajor)
                    acc[ct] = __builtin_amdgcn_mfma_f32_16x16x32_bf16(xf, wf, acc[ct], 0, 0, 0);
                else
                    acc[ct] = __builtin_amdgcn_mfma_f32_16x16x32_bf16(wf, xf, acc[ct], 0, 0, 0);
            }
        }
    }

    if (cmajor == 0) {
        int px = n0 + w * 16 + l15;
#pragma unroll
        for (int ct = 0; ct < 8; ct++) {
            int ci0 = ct * 16 + quad * 4;
            uint2 pk;
            pk.x = (u32)f2bf(acc[ct][0] + bias[ci0 + 0]) |
                   ((u32)f2bf(acc[ct][1] + bias[ci0 + 1]) << 16);
            pk.y = (u32)f2bf(acc[ct][2] + bias[ci0 + 2]) |
                   ((u32)f2bf(acc[ct][3] + bias[ci0 + 3]) << 16);
            *(uint2*)&out[(size_t)(b * Mn + px) * kCI + ci0] = pk;
        }
    } else {
        int px = n0 + w * 16 + quad * 4;
#pragma unroll
        for (int ct = 0; ct < 8; ct++) {
            int ci = ct * 16 + l15;
            float bs = bias[ci];
            uint2 pk;
            pk.x = (u32)f2bf(acc[ct][0] + bs) | ((u32)f2bf(acc[ct][1] + bs) << 16);
            pk.y = (u32)f2bf(acc[ct][2] + bs) | ((u32)f2bf(acc[ct][3] + bs) << 16);
            *(uint2*)&out[(size_t)(b * kCI + ci) * Mn + px] = pk;
        }
    }
}

// merged convs: bx<64: theta (no pool, n-major); bx<80: phi (pool, n-major);
// else: g (pool, ci-major). grid (96, 8) = 768 blocks -> 3 blocks/CU.
__global__ __launch_bounds__(256) void convs_kernel(const float* __restrict__ kin,
                                                    const float* __restrict__ qin,
                                                    const float* __restrict__ vin,
                                                    const u16* __restrict__ Wthb,
                                                    const u16* __restrict__ Wphb,
                                                    const u16* __restrict__ Wgb,
                                                    const float* __restrict__ bth,
                                                    const float* __restrict__ bph,
                                                    const float* __restrict__ bg,
                                                    u16* __restrict__ theta,
                                                    u16* __restrict__ phi,
                                                    u16* __restrict__ g) {
    __shared__ __align__(16) u16 w_lds[128 * 72];
    __shared__ __align__(16) u16 x_lds[64 * 64];
    int bx = blockIdx.x, b = blockIdx.y;
    if (bx < 64)
        conv_body<0>(kin, Wthb, bth, theta, kN, 0, b, bx * 64, w_lds, x_lds);
    else if (bx < 80)
        conv_body<1>(qin, Wphb, bph, phi, kM, 0, b, (bx - 64) * 64, w_lds, x_lds);
    else
        conv_body<1>(vin, Wgb, bg, g, kM, 1, b, (bx - 80) * 64, w_lds, x_lds);
}

// ---------------------------------------------------------------------------
// Barrier-free streaming flash attention, bf16 MFMA, ZERO LDS,
// in-wave software pipeline (register-double-buffered phi frags; g loads
// issued a softmax-phase ahead of use; no load is waited at vmcnt(0)).
// theta [B][N][CI], phi [B][M][CI], g [B][CI][M] (bf16); y bf16 [B][N][CI].
// One wave per block (64 thr, launch_bounds(64,1) -> up to 512 VGPR);
// wave owns 32 n; m-chunks of 64; no __syncthreads anywhere.
// ---------------------------------------------------------------------------
__global__ __launch_bounds__(64, 1) void attn_kernel(const u16* __restrict__ theta,
                                                     const u16* __restrict__ phi,
                                                     const u16* __restrict__ g,
                                                     u16* __restrict__ y) {
    int b = blockIdx.y, n0 = blockIdx.x * 32;
    int lane = threadIdx.x & 63, l15 = lane & 15, quad = lane >> 4;

    const u16* phB = phi + (size_t)b * kM * kCI;
    const u16* gB  = g   + (size_t)b * kCI * kM;

    // theta B-frags: register-resident for the whole kernel (32 n per wave)
    bf16x8 thf[2][4];
    const u16* thB = theta + ((size_t)(b * kN) + n0) * kCI;
#pragma unroll
    for (int nt = 0; nt < 2; nt++)
#pragma unroll
        for (int ks = 0; ks < 4; ks++)
            thf[nt][ks] = *(const bf16x8*)&thB[(size_t)(nt * 16 + l15) * kCI + ks * 32 + quad * 8];

    f32x4 oacc[8][2];
#pragma unroll
    for (int ct = 0; ct < 8; ct++) {
        oacc[ct][0] = (f32x4){0.f, 0.f, 0.f, 0.f};
        oacc[ct][1] = (f32x4){0.f, 0.f, 0.f, 0.f};
    }
    float m_[2] = {-1e30f, -1e30f}, l_[2] = {0.f, 0.f};

    // phi A-frag double buffer; preload chunk 0 into pf[0]
    bf16x8 pf[2][4][4];
#pragma unroll
    for (int mt = 0; mt < 4; mt++)
#pragma unroll
        for (int ks = 0; ks < 4; ks++)
            pf[0][mt][ks] = *(const bf16x8*)&phB[(size_t)(mt * 16 + l15) * kCI +
                                                 ks * 32 + quad * 8];

#pragma unroll 2
    for (int cidx = 0; cidx < 16; cidx++) {
        int cur = cidx & 1, nxt = cur ^ 1;
        int c0 = cidx * 64;

        // ---- issue NEXT chunk's phi loads (consumed next iteration) ----
        if (cidx < 15) {
            int c0n = c0 + 64;
#pragma unroll
            for (int mt = 0; mt < 4; mt++)
#pragma unroll
                for (int ks = 0; ks < 4; ks++)
                    pf[nxt][mt][ks] = *(const bf16x8*)&phB[(size_t)(c0n + mt * 16 + l15) * kCI +
                                                           ks * 32 + quad * 8];
        }
        // ---- issue THIS chunk's g loads (consumed after softmax) ----
        bf16x8 gf[2][8];
#pragma unroll
        for (int ks2 = 0; ks2 < 2; ks2++)
#pragma unroll
            for (int ct = 0; ct < 8; ct++)
                gf[ks2][ct] = *(const bf16x8*)&gB[(size_t)(ct * 16 + l15) * kM + c0 +
                                                  ks2 * 32 + quad * 8];

        // ---- S' = phi(64m x 128k) . theta^T ; pf[cur] loads long in flight ----
        f32x4 sacc[4][2];
#pragma unroll
        for (int mt = 0; mt < 4; mt++) {
            sacc[mt][0] = (f32x4){0.f, 0.f, 0.f, 0.f};
            sacc[mt][1] = (f32x4){0.f, 0.f, 0.f, 0.f};
        }
#pragma unroll
        for (int ks = 0; ks < 4; ks++)
#pragma unroll
            for (int mt = 0; mt < 4; mt++) {
                sacc[mt][0] = __builtin_amdgcn_mfma_f32_16x16x32_bf16(pf[cur][mt][ks], thf[0][ks],
                                                                      sacc[mt][0], 0, 0, 0);
                sacc[mt][1] = __builtin_amdgcn_mfma_f32_16x16x32_bf16(pf[cur][mt][ks], thf[1][ks],
                                                                      sacc[mt][1], 0, 0, 0);
            }

        // ---- online softmax per nt (C-col = n = l15; rows m across quad,reg)
        u32 d[2][4][2];
#pragma unroll
        for (int nt = 0; nt < 2; nt++) {
            float mc = -1e30f;
#pragma unroll
            for (int mt = 0; mt < 4; mt++)
#pragma unroll
                for (int r = 0; r < 4; r++) mc = fmaxf(mc, sacc[mt][nt][r]);
            mc = fmaxf(mc, __shfl_xor(mc, 16, 64));
            mc = fmaxf(mc, __shfl_xor(mc, 32, 64));
            float mn = fmaxf(m_[nt], mc);
            int resc = __any(mn != m_[nt]);
            float alpha = __expf(m_[nt] - mn);
            m_[nt] = mn;
            float rs = 0.f;
#pragma unroll
            for (int mt = 0; mt < 4; mt++)
#pragma unroll
                for (int r = 0; r < 4; r++) {
                    float p = __expf(sacc[mt][nt][r] - mn);
                    sacc[mt][nt][r] = p;
                    rs += p;
                }
            rs += __shfl_xor(rs, 16, 64);
            rs += __shfl_xor(rs, 32, 64);
            l_[nt] = l_[nt] * alpha + rs;
            if (resc) {
#pragma unroll
                for (int ct = 0; ct < 8; ct++)
#pragma unroll
                    for (int r = 0; r < 4; r++) oacc[ct][nt][r] *= alpha;
            }
#pragma unroll
            for (int mt = 0; mt < 4; mt++)
#pragma unroll
                for (int h = 0; h < 2; h++)
                    d[nt][mt][h] = (u32)f2bf(sacc[mt][nt][2 * h]) |
                                   ((u32)f2bf(sacc[mt][nt][2 * h + 1]) << 16);
        }

        // ---- O' += G^T(128ci x 64m) . P'(64m x 32n); gf loads covered by softmax
#pragma unroll
        for (int ks2 = 0; ks2 < 2; ks2++) {
            union { u32 u[4]; bf16x8 v; } bu[2];
#pragma unroll
            for (int nt = 0; nt < 2; nt++)
#pragma unroll
                for (int jj = 0; jj < 4; jj++) {
                    int srcl = 16 * ((quad & 1) * 2 + (jj >> 1)) + l15;
                    u32 va = (u32)__shfl((int)d[nt][ks2 * 2 + 0][jj & 1], srcl, 64);
                    u32 vb = (u32)__shfl((int)d[nt][ks2 * 2 + 1][jj & 1], srcl, 64);
                    bu[nt].u[jj] = (quad >> 1) ? vb : va;
                }
#pragma unroll
            for (int ct = 0; ct < 8; ct++) {
                oacc[ct][0] = __builtin_amdgcn_mfma_f32_16x16x32_bf16(gf[ks2][ct], bu[0].v, oacc[ct][0], 0, 0, 0);
                oacc[ct][1] = __builtin_amdgcn_mfma_f32_16x16x32_bf16(gf[ks2][ct], bu[1].v, oacc[ct][1], 0, 0, 0);
            }
        }
    }

    // ---- epilogue: y[n][ci] = O'/l ; n = col = l15
#pragma unroll
    for (int nt = 0; nt < 2; nt++) {
        float inv = 1.0f / l_[nt];
        int n = n0 + nt * 16 + l15;
        u16* yr = y + ((size_t)(b * kN) + n) * kCI + quad * 4;
#pragma unroll
        for (int ct = 0; ct < 8; ct++) {
            uint2 pk;
            pk.x = (u32)f2bf(oacc[ct][nt][0] * inv) | ((u32)f2bf(oacc[ct][nt][1] * inv) << 16);
            pk.y = (u32)f2bf(oacc[ct][nt][2] * inv) | ((u32)f2bf(oacc[ct][nt][3] * inv) << 16);
            *(uint2*)&yr[ct * 16] = pk;
        }
    }
}

// ---------------------------------------------------------------------------
// Barrier-free MFMA final conv: out[b][co][n] = Wws . y + bb[co] + v  (fp32)
// One wave per block; wave owns 16 n x 256 co; streamed from L2, no LDS.
// ---------------------------------------------------------------------------
__global__ __launch_bounds__(64, 1) void final_kernel(const u16* __restrict__ y,
                                                      const u16* __restrict__ Wws,
                                                      const float* __restrict__ bb,
                                                      const float* __restrict__ v,
                                                      float* __restrict__ out) {
    int b = blockIdx.y, n0 = blockIdx.x * 16;
    int lane = threadIdx.x & 63, l15 = lane & 15, quad = lane >> 4;

    bf16x8 af[4];
#pragma unroll
    for (int ks = 0; ks < 4; ks++)
        af[ks] = *(const bf16x8*)&y[(size_t)(b * kN + n0 + l15) * kCI + ks * 32 + quad * 8];

#pragma unroll
    for (int ct = 0; ct < 16; ct++) {
        f32x4 a = (f32x4){0.f, 0.f, 0.f, 0.f};
#pragma unroll
        for (int ks = 0; ks < 4; ks++) {
            bf16x8 bf = *(const bf16x8*)&Wws[(ct * 16 + l15) * kCI + ks * 32 + quad * 8];
            a = __builtin_amdgcn_mfma_f32_16x16x32_bf16(af[ks], bf, a, 0, 0, 0);
        }
        int co = ct * 16 + l15;
        float bbv = bb[co];
        size_t base = (size_t)(b * kC + co) * kN + n0 + quad * 4;
        float4 vv = *(const float4*)&v[base];
        float4 ov;
        ov.x = a[0] + bbv + vv.x;
        ov.y = a[1] + bbv + vv.y;
        ov.z = a[2] + bbv + vv.z;
        ov.w = a[3] + bbv + vv.w;
        *(float4*)&out[base] = ov;
    }
}

// ---------------------------------------------------------------------------
extern "C" void kernel_launch(void* const* d_in, const int* in_sizes, int n_in,
                              void* d_out, int out_size, void* d_ws, size_t ws_size,
                              hipStream_t stream) {
    (void)in_sizes; (void)n_in; (void)out_size; (void)ws_size;
    const float* q     = (const float*)d_in[0];
    const float* k     = (const float*)d_in[1];
    const float* v     = (const float*)d_in[2];
    const float* Wg    = (const float*)d_in[3];
    const float* bg    = (const float*)d_in[4];
    const float* Wth   = (const float*)d_in[5];
    const float* bth   = (const float*)d_in[6];
    const float* Wph   = (const float*)d_in[7];
    const float* bph   = (const float*)d_in[8];
    const float* Ww    = (const float*)d_in[9];
    const float* bw    = (const float*)d_in[10];
    const float* gamma = (const float*)d_in[11];
    const float* beta  = (const float*)d_in[12];
    const float* mean  = (const float*)d_in[13];
    const float* var   = (const float*)d_in[14];
    float* out = (float*)d_out;

    u16* wsu = (u16*)d_ws;
    u16*   theta = wsu;                       // 4M u16
    u16*   phi   = theta + 4194304;           // 1M u16
    u16*   gbuf  = phi + 1048576;             // 1M u16
    u16*   ybuf  = gbuf + 1048576;            // 4M u16
    u16*   Wthb  = ybuf + 4194304;
    u16*   Wphb  = Wthb + 32768;
    u16*   Wgb   = Wphb + 32768;
    u16*   Wwsb  = Wgb + 32768;
    float* bbuf  = (float*)(Wwsb + 32768);

    prep_kernel<<<dim3(512), 256, 0, stream>>>(Wth, Wph, Wg, Ww, bw, gamma, beta,
                                               mean, var, Wthb, Wphb, Wgb, Wwsb, bbuf);
    convs_kernel<<<dim3(96, 8), 256, 0, stream>>>(k, q, v, Wthb, Wphb, Wgb,
                                                  bth, bph, bg, theta, phi, gbuf);
    attn_kernel<<<dim3(128, 8), 64, 0, stream>>>(theta, phi, gbuf, ybuf);
    final_kernel<<<dim3(256, 8), 64, 0, stream>>>(ybuf, Wwsb, bbuf, v, out);
}